// Round 9
// baseline (466.173 us; speedup 1.0000x reference)
//
#include <hip/hip_runtime.h>
#include <stdint.h>

#define TT 2048
#define BB 4
#define HH 768
#define NHEADS 4
#define DD 768
#define NN 3072   // NHEADS*DD
#define LL 3
#define BT 8192   // BB*TT
#define KNB 5
#define NBLK 12   // 64-col partial blocks per head (DD/64)

typedef __bf16 bf16x8 __attribute__((ext_vector_type(8)));
typedef float f32x4 __attribute__((ext_vector_type(4)));

__device__ __forceinline__ unsigned short f2bf(float f){
  union { float f; unsigned u; } v; v.f = f;
  unsigned u = v.u;
  return (unsigned short)((u + 0x7FFFu + ((u >> 16) & 1u)) >> 16);
}
__device__ __forceinline__ float bf2f(unsigned short h){
  union { unsigned u; float f; } v; v.u = ((unsigned)h) << 16;
  return v.f;
}
// async global->LDS, 16B per lane; LDS dest = wave-uniform base + lane*16
__device__ __forceinline__ void gload16(const unsigned short* g, unsigned short* l){
  __builtin_amdgcn_global_load_lds((const __attribute__((address_space(1))) void*)g,
                                   (__attribute__((address_space(3))) void*)l, 16, 0, 0);
}

// ---------------- W transpose + bf16 convert: W[l][k][n] fp32 -> Wt[l][n][k] bf16
__global__ void wt_kernel(const float* __restrict__ W, unsigned short* __restrict__ Wt){
  __shared__ float tile[32][33];
  int l = blockIdx.z;
  int n0 = blockIdx.x * 32, k0 = blockIdx.y * 32;
  int tx = threadIdx.x, ty = threadIdx.y; // (32,8)
  const float* Wl = W + (size_t)l * HH * NN;
  for (int r = 0; r < 4; r++)
    tile[ty + r*8][tx] = Wl[(size_t)(k0 + ty + r*8) * NN + n0 + tx];
  __syncthreads();
  unsigned short* Wtl = Wt + (size_t)l * NN * HH;
  for (int r = 0; r < 4; r++){
    int n = n0 + ty + r*8;
    Wtl[(size_t)n * HH + k0 + tx] = f2bf(tile[tx][ty + r*8]);
  }
}

// ---------------- x fp32 -> bf16 (layer 0 GEMM input)
__global__ void xconv_kernel(const float* __restrict__ x, unsigned short* __restrict__ xb){
  int i = blockIdx.x * blockDim.x + threadIdx.x;
  float4 v = ((const float4*)x)[i];
  ushort4 o;
  o.x = f2bf(v.x); o.y = f2bf(v.y); o.z = f2bf(v.z); o.w = f2bf(v.w);
  *(ushort4*)(xb + (size_t)i * 4) = o;
}

// ---------------- GEMM (R6 K-loop, FROZEN — verified best 4x):
// R12 (256² 4-phase unroll2): spilled, 92us. R15 (128² 2-phase dbuf): lost
// 3rd block/CU, 66us. R16 (256² 4-phase unroll1): 1 block/CU, 75us.
// R18 (B direct from global): +32 live VGPR across barrier -> spills, 64us.
// Lesson: this 2-barrier loop at 3 blocks/CU TLP is the measured optimum for
// K=768; every extra live register or LDS byte costs more than it buys.
#define BM 128
#define BN 128
#define BK 64

__global__ __launch_bounds__(256, 3) void gemm_kernel(
    const unsigned short* __restrict__ xb,
    const unsigned short* __restrict__ wt,
    unsigned short* __restrict__ hout,
    const float* __restrict__ a_srcl,
    const float* __restrict__ a_dstl,
    float* __restrict__ psrc,     // [BT][NHEADS][NBLK]
    float* __restrict__ pdst){
  __shared__ __align__(16) unsigned short xs[BM][BK];   // 16 KB
  __shared__ __align__(16) unsigned short wsd[BN][BK];  // 16 KB
  // XCD-aware remap: per-XCD 8-row bm band, bn-major within the band so the
  // xb band (1.6 MB) stays L2-resident and wt slices stream through.
  int id = blockIdx.x;              // 1536
  int xcd = id & 7;
  int s = id >> 3;                  // 0..191
  int bn_i = s / 8;                 // 0..23
  int bm_i = (s & 7) + xcd * 8;     // 0..63
  int bm = bm_i * BM;
  int bn = bn_i * BN;
  int tid = threadIdx.x;
  int wave = tid >> 6, lane = tid & 63;
  int m16 = lane & 15, q = lane >> 4;
  int wm = (wave >> 1) * 64, wn = (wave & 1) * 64;
  int r8 = lane >> 3, c8 = lane & 7;
  int cg = (c8 ^ r8) * 8;     // fetched chunk: position c8 holds global chunk c8^(row&7)
  const unsigned short* ga[4]; const unsigned short* gb[4];
  unsigned short* la[4]; unsigned short* lb[4];
  #pragma unroll
  for (int ss = 0; ss < 4; ss++){
    int row = wave * 32 + ss * 8;
    ga[ss] = xb + (size_t)(bm + row + r8) * HH + cg;
    gb[ss] = wt + (size_t)(bn + row + r8) * HH + cg;
    la[ss] = &xs[row][0];
    lb[ss] = &wsd[row][0];
  }
  int rd0 = ((0 + q) ^ (m16 & 7)) * 8;   // ks=0 fragment chunk offset
  int rd1 = ((4 + q) ^ (m16 & 7)) * 8;   // ks=1
  f32x4 acc[4][4] = {};
  for (int k0 = 0; k0 < HH; k0 += BK){
    #pragma unroll
    for (int ss = 0; ss < 4; ss++){
      gload16(ga[ss] + k0, la[ss]);
      gload16(gb[ss] + k0, lb[ss]);
    }
    __syncthreads();
    bf16x8 af[4], bfr[4];
    for (int i = 0; i < 4; i++)
      af[i] = __builtin_bit_cast(bf16x8, *(const uint4*)(&xs[wm + i*16 + m16][rd0]));
    for (int j = 0; j < 4; j++)
      bfr[j] = __builtin_bit_cast(bf16x8, *(const uint4*)(&wsd[wn + j*16 + m16][rd0]));
    for (int i = 0; i < 4; i++)
      for (int j = 0; j < 4; j++)
        acc[i][j] = __builtin_amdgcn_mfma_f32_16x16x32_bf16(af[i], bfr[j], acc[i][j], 0, 0, 0);
    for (int i = 0; i < 4; i++)
      af[i] = __builtin_bit_cast(bf16x8, *(const uint4*)(&xs[wm + i*16 + m16][rd1]));
    for (int j = 0; j < 4; j++)
      bfr[j] = __builtin_bit_cast(bf16x8, *(const uint4*)(&wsd[wn + j*16 + m16][rd1]));
    for (int i = 0; i < 4; i++)
      for (int j = 0; j < 4; j++)
        acc[i][j] = __builtin_amdgcn_mfma_f32_16x16x32_bf16(af[i], bfr[j], acc[i][j], 0, 0, 0);
    __syncthreads();
  }
  // C store (bf16)
  for (int i = 0; i < 4; i++){
    int row0 = bm + wm + i*16 + q*4;
    for (int j = 0; j < 4; j++){
      int col = bn + wn + j*16 + m16;
      unsigned short* hp = hout + (size_t)row0 * NN + col;
      hp[0]            = f2bf(acc[i][j][0]);
      hp[NN]           = f2bf(acc[i][j][1]);
      hp[2*(size_t)NN] = f2bf(acc[i][j][2]);
      hp[3*(size_t)NN] = f2bf(acc[i][j][3]);
    }
  }
  // fused asrc/adst partials: wave covers 64 cols = one (head, blk) slot
  int col0 = bn + wn;
  int head = col0 / DD;
  int blk  = (col0 % DD) >> 6;
  float wsrc[4], wdstw[4];
  for (int j = 0; j < 4; j++){
    int n = col0 + j*16 + m16;
    wsrc[j]  = a_srcl[n];
    wdstw[j] = a_dstl[n];
  }
  for (int i = 0; i < 4; i++){
    for (int reg = 0; reg < 4; reg++){
      float ss = 0.f, dd = 0.f;
      for (int j = 0; j < 4; j++){
        float v = acc[i][j][reg];
        ss += v * wsrc[j];
        dd += v * wdstw[j];
      }
      ss += __shfl_xor(ss, 1, 64); dd += __shfl_xor(dd, 1, 64);
      ss += __shfl_xor(ss, 2, 64); dd += __shfl_xor(dd, 2, 64);
      ss += __shfl_xor(ss, 4, 64); dd += __shfl_xor(dd, 4, 64);
      ss += __shfl_xor(ss, 8, 64); dd += __shfl_xor(dd, 8, 64);
      if (m16 == 0){
        int row = bm + wm + i*16 + q*4 + reg;
        size_t slot = (size_t)row * (NHEADS * NBLK) + head * NBLK + blk;
        psrc[slot] = ss;
        pdst[slot] = dd;
      }
    }
  }
}

// ---------------- attention + head-mean + bias + residual + layernorm
// R20 = R19 (wave-per-token, softmax-first, zero barriers/LDS) with
// __launch_bounds__(512, 4): R6's counters revealed attn runs at VGPR=64
// (hipcc's default for LB(512) targets 8 waves/SIMD), which forces aw/sc
// spills in every variant and explains both the ~49us plateau and R17's
// catastrophic scratch traffic. (512,4) lifts the cap to 128 VGPR at
// 4 waves/SIMD (16 waves/CU — ample TLP for fully-independent waves).
__global__ __launch_bounds__(512, 4) void attn_ln_kernel(const unsigned short* __restrict__ h,
    const float* __restrict__ psrc, const float* __restrict__ pdst,
    const float* __restrict__ xin_f32,          // non-null => layer 0 residual (fp32)
    const unsigned short* __restrict__ xin_bf,  // else residual from bf16 xb
    const float* __restrict__ bias_l,
    const float* __restrict__ gamma_l, const float* __restrict__ beta_l,
    float* __restrict__ x_out, unsigned short* __restrict__ xb_next,
    int write_f32){
  int bid = blockIdx.x;                       // 1024 blocks x 8 waves
  int grp = ((bid & 7) << 7) | (bid >> 3);    // XCD-contiguous 1024-token bands
  int wave = threadIdx.x >> 6, lane = threadIdx.x & 63;
  int token = grp * 8 + wave;
  int t = token & (TT - 1);
  int bseq = token >> 11;

  // srcred: lanes 0..19 hold as[k][hd] (window row k=lane>>2, head=lane&3);
  // lanes 20..23 hold ad[hd] for this token. Each sums 12 partial floats.
  float red = 0.f;
  if (lane < 24){
    const float* p;
    if (lane < 20){
      int k = lane >> 2, hd = lane & 3;
      int row = min(max(t - 2 + k, 0), TT - 1);
      p = psrc + ((size_t)(bseq * TT + row) * NHEADS + hd) * NBLK;
    } else {
      int hd = lane - 20;
      p = pdst + ((size_t)(bseq * TT + t) * NHEADS + hd) * NBLK;
    }
    float4 a = *(const float4*)(p);
    float4 b = *(const float4*)(p + 4);
    float4 d = *(const float4*)(p + 8);
    red = a.x+a.y+a.z+a.w + b.x+b.y+b.z+b.w + d.x+d.y+d.z+d.w;
  }

  // ---- all-heads softmax first (redundant across lanes; shfl ~ free) ----
  float aw[NHEADS][KNB];
  #pragma unroll
  for (int hd = 0; hd < NHEADS; hd++){
    float ad = __shfl(red, 20 + hd, 64);
    float sc[KNB];
    float mx = -3.0e38f;
    #pragma unroll
    for (int k = 0; k < KNB; k++){
      int tn = t + k - 2;                 // wave-uniform branch
      if (tn >= 0 && tn < TT){
        float s = __shfl(red, k * 4 + hd, 64) + ad;
        s = s > 0.f ? s : 0.2f * s;       // leaky_relu 0.2
        sc[k] = s; mx = fmaxf(mx, s);
      } else sc[k] = -3.0e38f;
    }
    float den = 0.f;
    #pragma unroll
    for (int k = 0; k < KNB; k++){
      float e = (sc[k] > -1.0e38f) ? __expf(sc[k] - mx) : 0.f;
      sc[k] = e; den += e;
    }
    float inv = 0.25f / den;              // fold 1/HEADS into attn
    #pragma unroll
    for (int k = 0; k < KNB; k++) aw[hd][k] = sc[k] * inv;
  }

  // ---- flat PV stream: 60 independent uint2 loads + FMAs, no exp between.
  // Lane owns elems lane*4 + j*256, j=0..2.
  const unsigned short* hb = h + (size_t)(bseq * TT) * NN + lane * 4;
  float y[12] = {};
  #pragma unroll
  for (int k = 0; k < KNB; k++){
    int g = t + k - 2;
    g = min(max(g, 0), TT - 1);
    const unsigned short* hr = hb + (size_t)g * NN;
    #pragma unroll
    for (int hd = 0; hd < NHEADS; hd++){
      const unsigned short* hp = hr + hd * DD;
      float a = aw[hd][k];
      #pragma unroll
      for (int j = 0; j < 3; j++){
        uint2 u = *(const uint2*)(hp + j * 256);
        const unsigned short* us = (const unsigned short*)&u;
        y[j*4+0] += a * bf2f(us[0]);
        y[j*4+1] += a * bf2f(us[1]);
        y[j*4+2] += a * bf2f(us[2]);
        y[j*4+3] += a * bf2f(us[3]);
      }
    }
  }

  // residual + bias, accumulate LN stats
  float xr[12], bb[12];
  if (xin_f32){
    const float* xp = xin_f32 + (size_t)token * HH + lane * 4;
    #pragma unroll
    for (int j = 0; j < 3; j++) *(float4*)&xr[j*4] = *(const float4*)(xp + j * 256);
  } else {
    const unsigned short* xp = xin_bf + (size_t)token * HH + lane * 4;
    #pragma unroll
    for (int j = 0; j < 3; j++){
      uint2 u = *(const uint2*)(xp + j * 256);
      const unsigned short* us = (const unsigned short*)&u;
      xr[j*4+0] = bf2f(us[0]); xr[j*4+1] = bf2f(us[1]);
      xr[j*4+2] = bf2f(us[2]); xr[j*4+3] = bf2f(us[3]);
    }
  }
  { const float* p = bias_l + lane * 4;
    #pragma unroll
    for (int j = 0; j < 3; j++) *(float4*)&bb[j*4] = *(const float4*)(p + j * 256); }
  float s = 0.f, sq = 0.f;
  #pragma unroll
  for (int e = 0; e < 12; e++){
    float zz = y[e] + bb[e] + xr[e];
    y[e] = zz; s += zz; sq += zz * zz;
  }
  // wave-level LN reduce (no LDS, no barrier)
  #pragma unroll
  for (int off = 32; off > 0; off >>= 1){
    s  += __shfl_xor(s, off, 64);
    sq += __shfl_xor(sq, off, 64);
  }
  float mean = s * (1.f / HH);
  float var = sq * (1.f / HH) - mean * mean;
  float rstd = rsqrtf(var + 1e-5f);

  float gr[12], br[12];
  { const float* p = gamma_l + lane * 4;
    #pragma unroll
    for (int j = 0; j < 3; j++) *(float4*)&gr[j*4] = *(const float4*)(p + j * 256); }
  { const float* p = beta_l + lane * 4;
    #pragma unroll
    for (int j = 0; j < 3; j++) *(float4*)&br[j*4] = *(const float4*)(p + j * 256); }

  float o[12];
  #pragma unroll
  for (int e = 0; e < 12; e++)
    o[e] = (y[e] - mean) * rstd * gr[e] + br[e];

  if (write_f32){
    float* xo = x_out + (size_t)token * HH + lane * 4;
    #pragma unroll
    for (int j = 0; j < 3; j++) *(float4*)(xo + j * 256) = *(float4*)&o[j*4];
  } else {
    unsigned short* xo = xb_next + (size_t)token * HH + lane * 4;
    #pragma unroll
    for (int j = 0; j < 3; j++){
      ushort4 o16;
      o16.x = f2bf(o[j*4+0]); o16.y = f2bf(o[j*4+1]);
      o16.z = f2bf(o[j*4+2]); o16.w = f2bf(o[j*4+3]);
      *(ushort4*)(xo + j * 256) = o16;
    }
  }
}

extern "C" void kernel_launch(void* const* d_in, const int* in_sizes, int n_in,
                              void* d_out, int out_size, void* d_ws, size_t ws_size,
                              hipStream_t stream) {
  const float* x     = (const float*)d_in[0];
  const float* W     = (const float*)d_in[1];
  const float* a_src = (const float*)d_in[2];
  const float* a_dst = (const float*)d_in[3];
  const float* bias  = (const float*)d_in[4];
  const float* gamma = (const float*)d_in[5];
  const float* beta  = (const float*)d_in[6];
  float* out = (float*)d_out;

  char* ws = (char*)d_ws;
  size_t off = 0;
  auto alloc = [&](size_t bytes)->char*{
    char* p = ws + off;
    off = (off + bytes + 255) & ~(size_t)255;
    return p;
  };
  unsigned short* wt   = (unsigned short*)alloc((size_t)LL * NN * HH * 2);
  unsigned short* xb   = (unsigned short*)alloc((size_t)BT * HH * 2);
  unsigned short* hbuf = (unsigned short*)alloc((size_t)BT * NN * 2);
  float* psrc  = (float*)alloc((size_t)BT * NHEADS * NBLK * 4);
  float* pdst  = (float*)alloc((size_t)BT * NHEADS * NBLK * 4);

  wt_kernel<<<dim3(NN/32, HH/32, LL), dim3(32, 8), 0, stream>>>(W, wt);
  xconv_kernel<<<(BT * HH / 4) / 256, 256, 0, stream>>>(x, xb);

  for (int l = 0; l < LL; l++){
    gemm_kernel<<<(NN / BN) * (BT / BM), 256, 0, stream>>>(
        xb, wt + (size_t)l * NN * HH, hbuf,
        a_src + (size_t)l * NHEADS * DD, a_dst + (size_t)l * NHEADS * DD,
        psrc, pdst);
    attn_ln_kernel<<<BT / 8, 512, 0, stream>>>(hbuf, psrc, pdst,
        (l == 0) ? x : nullptr, xb,
        bias + (size_t)l * DD, gamma + (size_t)l * HH, beta + (size_t)l * HH,
        out, xb, (l == LL - 1) ? 1 : 0);
  }
}

// Round 10
// 449.876 us; speedup vs baseline: 1.0362x; 1.0362x over previous
//
#include <hip/hip_runtime.h>
#include <stdint.h>

#define TT 2048
#define BB 4
#define HH 768
#define NHEADS 4
#define DD 768
#define NN 3072   // NHEADS*DD
#define LL 3
#define BT 8192   // BB*TT
#define KNB 5
#define NBLK 12   // 64-col partial blocks per head (DD/64)

typedef __bf16 bf16x8 __attribute__((ext_vector_type(8)));
typedef float f32x4 __attribute__((ext_vector_type(4)));

__device__ __forceinline__ unsigned short f2bf(float f){
  union { float f; unsigned u; } v; v.f = f;
  unsigned u = v.u;
  return (unsigned short)((u + 0x7FFFu + ((u >> 16) & 1u)) >> 16);
}
__device__ __forceinline__ float bf2f(unsigned short h){
  union { unsigned u; float f; } v; v.u = ((unsigned)h) << 16;
  return v.f;
}
// async global->LDS, 16B per lane; LDS dest = wave-uniform base + lane*16
__device__ __forceinline__ void gload16(const unsigned short* g, unsigned short* l){
  __builtin_amdgcn_global_load_lds((const __attribute__((address_space(1))) void*)g,
                                   (__attribute__((address_space(3))) void*)l, 16, 0, 0);
}

// ---------------- W transpose + bf16 convert: W[l][k][n] fp32 -> Wt[l][n][k] bf16
__global__ void wt_kernel(const float* __restrict__ W, unsigned short* __restrict__ Wt){
  __shared__ float tile[32][33];
  int l = blockIdx.z;
  int n0 = blockIdx.x * 32, k0 = blockIdx.y * 32;
  int tx = threadIdx.x, ty = threadIdx.y; // (32,8)
  const float* Wl = W + (size_t)l * HH * NN;
  for (int r = 0; r < 4; r++)
    tile[ty + r*8][tx] = Wl[(size_t)(k0 + ty + r*8) * NN + n0 + tx];
  __syncthreads();
  unsigned short* Wtl = Wt + (size_t)l * NN * HH;
  for (int r = 0; r < 4; r++){
    int n = n0 + ty + r*8;
    Wtl[(size_t)n * HH + k0 + tx] = f2bf(tile[tx][ty + r*8]);
  }
}

// ---------------- x fp32 -> bf16 (layer 0 GEMM input)
__global__ void xconv_kernel(const float* __restrict__ x, unsigned short* __restrict__ xb){
  int i = blockIdx.x * blockDim.x + threadIdx.x;
  float4 v = ((const float4*)x)[i];
  ushort4 o;
  o.x = f2bf(v.x); o.y = f2bf(v.y); o.z = f2bf(v.z); o.w = f2bf(v.w);
  *(ushort4*)(xb + (size_t)i * 4) = o;
}

// ---------------- GEMM (R6 K-loop, FROZEN — verified best 4x):
// R12 (256² 4-phase unroll2): spilled, 92us. R15 (128² 2-phase dbuf): lost
// 3rd block/CU, 66us. R16 (256² 4-phase unroll1): 1 block/CU, 75us.
// R18 (B direct from global): +32 live VGPR across barrier -> spills, 64us.
// Lesson: this 2-barrier loop at 3 blocks/CU TLP is the measured optimum for
// K=768; every extra live register or LDS byte costs more than it buys.
#define BM 128
#define BN 128
#define BK 64

__global__ __launch_bounds__(256, 3) void gemm_kernel(
    const unsigned short* __restrict__ xb,
    const unsigned short* __restrict__ wt,
    unsigned short* __restrict__ hout,
    const float* __restrict__ a_srcl,
    const float* __restrict__ a_dstl,
    float* __restrict__ psrc,     // [BT][NHEADS][NBLK]
    float* __restrict__ pdst){
  __shared__ __align__(16) unsigned short xs[BM][BK];   // 16 KB
  __shared__ __align__(16) unsigned short wsd[BN][BK];  // 16 KB
  // XCD-aware remap: per-XCD 8-row bm band, bn-major within the band so the
  // xb band (1.6 MB) stays L2-resident and wt slices stream through.
  int id = blockIdx.x;              // 1536
  int xcd = id & 7;
  int s = id >> 3;                  // 0..191
  int bn_i = s / 8;                 // 0..23
  int bm_i = (s & 7) + xcd * 8;     // 0..63
  int bm = bm_i * BM;
  int bn = bn_i * BN;
  int tid = threadIdx.x;
  int wave = tid >> 6, lane = tid & 63;
  int m16 = lane & 15, q = lane >> 4;
  int wm = (wave >> 1) * 64, wn = (wave & 1) * 64;
  int r8 = lane >> 3, c8 = lane & 7;
  int cg = (c8 ^ r8) * 8;     // fetched chunk: position c8 holds global chunk c8^(row&7)
  const unsigned short* ga[4]; const unsigned short* gb[4];
  unsigned short* la[4]; unsigned short* lb[4];
  #pragma unroll
  for (int ss = 0; ss < 4; ss++){
    int row = wave * 32 + ss * 8;
    ga[ss] = xb + (size_t)(bm + row + r8) * HH + cg;
    gb[ss] = wt + (size_t)(bn + row + r8) * HH + cg;
    la[ss] = &xs[row][0];
    lb[ss] = &wsd[row][0];
  }
  int rd0 = ((0 + q) ^ (m16 & 7)) * 8;   // ks=0 fragment chunk offset
  int rd1 = ((4 + q) ^ (m16 & 7)) * 8;   // ks=1
  f32x4 acc[4][4] = {};
  for (int k0 = 0; k0 < HH; k0 += BK){
    #pragma unroll
    for (int ss = 0; ss < 4; ss++){
      gload16(ga[ss] + k0, la[ss]);
      gload16(gb[ss] + k0, lb[ss]);
    }
    __syncthreads();
    bf16x8 af[4], bfr[4];
    for (int i = 0; i < 4; i++)
      af[i] = __builtin_bit_cast(bf16x8, *(const uint4*)(&xs[wm + i*16 + m16][rd0]));
    for (int j = 0; j < 4; j++)
      bfr[j] = __builtin_bit_cast(bf16x8, *(const uint4*)(&wsd[wn + j*16 + m16][rd0]));
    for (int i = 0; i < 4; i++)
      for (int j = 0; j < 4; j++)
        acc[i][j] = __builtin_amdgcn_mfma_f32_16x16x32_bf16(af[i], bfr[j], acc[i][j], 0, 0, 0);
    for (int i = 0; i < 4; i++)
      af[i] = __builtin_bit_cast(bf16x8, *(const uint4*)(&xs[wm + i*16 + m16][rd1]));
    for (int j = 0; j < 4; j++)
      bfr[j] = __builtin_bit_cast(bf16x8, *(const uint4*)(&wsd[wn + j*16 + m16][rd1]));
    for (int i = 0; i < 4; i++)
      for (int j = 0; j < 4; j++)
        acc[i][j] = __builtin_amdgcn_mfma_f32_16x16x32_bf16(af[i], bfr[j], acc[i][j], 0, 0, 0);
    __syncthreads();
  }
  // C store (bf16)
  for (int i = 0; i < 4; i++){
    int row0 = bm + wm + i*16 + q*4;
    for (int j = 0; j < 4; j++){
      int col = bn + wn + j*16 + m16;
      unsigned short* hp = hout + (size_t)row0 * NN + col;
      hp[0]            = f2bf(acc[i][j][0]);
      hp[NN]           = f2bf(acc[i][j][1]);
      hp[2*(size_t)NN] = f2bf(acc[i][j][2]);
      hp[3*(size_t)NN] = f2bf(acc[i][j][3]);
    }
  }
  // fused asrc/adst partials: wave covers 64 cols = one (head, blk) slot
  int col0 = bn + wn;
  int head = col0 / DD;
  int blk  = (col0 % DD) >> 6;
  float wsrc[4], wdstw[4];
  for (int j = 0; j < 4; j++){
    int n = col0 + j*16 + m16;
    wsrc[j]  = a_srcl[n];
    wdstw[j] = a_dstl[n];
  }
  for (int i = 0; i < 4; i++){
    for (int reg = 0; reg < 4; reg++){
      float ss = 0.f, dd = 0.f;
      for (int j = 0; j < 4; j++){
        float v = acc[i][j][reg];
        ss += v * wsrc[j];
        dd += v * wdstw[j];
      }
      ss += __shfl_xor(ss, 1, 64); dd += __shfl_xor(dd, 1, 64);
      ss += __shfl_xor(ss, 2, 64); dd += __shfl_xor(dd, 2, 64);
      ss += __shfl_xor(ss, 4, 64); dd += __shfl_xor(dd, 4, 64);
      ss += __shfl_xor(ss, 8, 64); dd += __shfl_xor(dd, 8, 64);
      if (m16 == 0){
        int row = bm + wm + i*16 + q*4 + reg;
        size_t slot = (size_t)row * (NHEADS * NBLK) + head * NBLK + blk;
        psrc[slot] = ss;
        pdst[slot] = dd;
      }
    }
  }
}

// ---------------- attention + head-mean + bias + residual + layernorm
// R21 = R19 body (wave-per-token, softmax-first, zero barriers/LDS) with
// 256-thread blocks + __launch_bounds__(256, 4) -> honest 128-VGPR cap at
// 16 waves/CU. R9 evidence: LB(512,4) provoked spill codegen (261 MB scratch,
// 74us) with VGPR still reported 64 — B=512 + min-waves arg is toxic on this
// toolchain; gemm's (256,3) works as documented (VGPR 68 > 64). This finally
// tests "PV stream is register-starved ILP" cleanly: 64-VGPR cap allows only
// ~7 of the 60 independent PV loads in flight; 128 allows ~30.
__global__ __launch_bounds__(256, 4) void attn_ln_kernel(const unsigned short* __restrict__ h,
    const float* __restrict__ psrc, const float* __restrict__ pdst,
    const float* __restrict__ xin_f32,          // non-null => layer 0 residual (fp32)
    const unsigned short* __restrict__ xin_bf,  // else residual from bf16 xb
    const float* __restrict__ bias_l,
    const float* __restrict__ gamma_l, const float* __restrict__ beta_l,
    float* __restrict__ x_out, unsigned short* __restrict__ xb_next,
    int write_f32){
  int bid = blockIdx.x;                       // 2048 blocks x 4 waves
  int grp = ((bid & 7) << 8) | (bid >> 3);    // XCD-contiguous 1024-token bands
  int wave = threadIdx.x >> 6, lane = threadIdx.x & 63;
  int token = grp * 4 + wave;
  int t = token & (TT - 1);
  int bseq = token >> 11;

  // srcred: lanes 0..19 hold as[k][hd] (window row k=lane>>2, head=lane&3);
  // lanes 20..23 hold ad[hd] for this token. Each sums 12 partial floats.
  float red = 0.f;
  if (lane < 24){
    const float* p;
    if (lane < 20){
      int k = lane >> 2, hd = lane & 3;
      int row = min(max(t - 2 + k, 0), TT - 1);
      p = psrc + ((size_t)(bseq * TT + row) * NHEADS + hd) * NBLK;
    } else {
      int hd = lane - 20;
      p = pdst + ((size_t)(bseq * TT + t) * NHEADS + hd) * NBLK;
    }
    float4 a = *(const float4*)(p);
    float4 b = *(const float4*)(p + 4);
    float4 d = *(const float4*)(p + 8);
    red = a.x+a.y+a.z+a.w + b.x+b.y+b.z+b.w + d.x+d.y+d.z+d.w;
  }

  // ---- all-heads softmax first (redundant across lanes; shfl ~ free) ----
  float aw[NHEADS][KNB];
  #pragma unroll
  for (int hd = 0; hd < NHEADS; hd++){
    float ad = __shfl(red, 20 + hd, 64);
    float sc[KNB];
    float mx = -3.0e38f;
    #pragma unroll
    for (int k = 0; k < KNB; k++){
      int tn = t + k - 2;                 // wave-uniform branch
      if (tn >= 0 && tn < TT){
        float s = __shfl(red, k * 4 + hd, 64) + ad;
        s = s > 0.f ? s : 0.2f * s;       // leaky_relu 0.2
        sc[k] = s; mx = fmaxf(mx, s);
      } else sc[k] = -3.0e38f;
    }
    float den = 0.f;
    #pragma unroll
    for (int k = 0; k < KNB; k++){
      float e = (sc[k] > -1.0e38f) ? __expf(sc[k] - mx) : 0.f;
      sc[k] = e; den += e;
    }
    float inv = 0.25f / den;              // fold 1/HEADS into attn
    #pragma unroll
    for (int k = 0; k < KNB; k++) aw[hd][k] = sc[k] * inv;
  }

  // ---- flat PV stream: 60 independent uint2 loads + FMAs, no exp between.
  // Lane owns elems lane*4 + j*256, j=0..2.
  const unsigned short* hb = h + (size_t)(bseq * TT) * NN + lane * 4;
  float y[12] = {};
  #pragma unroll
  for (int k = 0; k < KNB; k++){
    int g = t + k - 2;
    g = min(max(g, 0), TT - 1);
    const unsigned short* hr = hb + (size_t)g * NN;
    #pragma unroll
    for (int hd = 0; hd < NHEADS; hd++){
      const unsigned short* hp = hr + hd * DD;
      float a = aw[hd][k];
      #pragma unroll
      for (int j = 0; j < 3; j++){
        uint2 u = *(const uint2*)(hp + j * 256);
        const unsigned short* us = (const unsigned short*)&u;
        y[j*4+0] += a * bf2f(us[0]);
        y[j*4+1] += a * bf2f(us[1]);
        y[j*4+2] += a * bf2f(us[2]);
        y[j*4+3] += a * bf2f(us[3]);
      }
    }
  }

  // residual + bias, accumulate LN stats
  float xr[12], bb[12];
  if (xin_f32){
    const float* xp = xin_f32 + (size_t)token * HH + lane * 4;
    #pragma unroll
    for (int j = 0; j < 3; j++) *(float4*)&xr[j*4] = *(const float4*)(xp + j * 256);
  } else {
    const unsigned short* xp = xin_bf + (size_t)token * HH + lane * 4;
    #pragma unroll
    for (int j = 0; j < 3; j++){
      uint2 u = *(const uint2*)(xp + j * 256);
      const unsigned short* us = (const unsigned short*)&u;
      xr[j*4+0] = bf2f(us[0]); xr[j*4+1] = bf2f(us[1]);
      xr[j*4+2] = bf2f(us[2]); xr[j*4+3] = bf2f(us[3]);
    }
  }
  { const float* p = bias_l + lane * 4;
    #pragma unroll
    for (int j = 0; j < 3; j++) *(float4*)&bb[j*4] = *(const float4*)(p + j * 256); }
  float s = 0.f, sq = 0.f;
  #pragma unroll
  for (int e = 0; e < 12; e++){
    float zz = y[e] + bb[e] + xr[e];
    y[e] = zz; s += zz; sq += zz * zz;
  }
  // wave-level LN reduce (no LDS, no barrier)
  #pragma unroll
  for (int off = 32; off > 0; off >>= 1){
    s  += __shfl_xor(s, off, 64);
    sq += __shfl_xor(sq, off, 64);
  }
  float mean = s * (1.f / HH);
  float var = sq * (1.f / HH) - mean * mean;
  float rstd = rsqrtf(var + 1e-5f);

  float gr[12], br[12];
  { const float* p = gamma_l + lane * 4;
    #pragma unroll
    for (int j = 0; j < 3; j++) *(float4*)&gr[j*4] = *(const float4*)(p + j * 256); }
  { const float* p = beta_l + lane * 4;
    #pragma unroll
    for (int j = 0; j < 3; j++) *(float4*)&br[j*4] = *(const float4*)(p + j * 256); }

  float o[12];
  #pragma unroll
  for (int e = 0; e < 12; e++)
    o[e] = (y[e] - mean) * rstd * gr[e] + br[e];

  if (write_f32){
    float* xo = x_out + (size_t)token * HH + lane * 4;
    #pragma unroll
    for (int j = 0; j < 3; j++) *(float4*)(xo + j * 256) = *(float4*)&o[j*4];
  } else {
    unsigned short* xo = xb_next + (size_t)token * HH + lane * 4;
    #pragma unroll
    for (int j = 0; j < 3; j++){
      ushort4 o16;
      o16.x = f2bf(o[j*4+0]); o16.y = f2bf(o[j*4+1]);
      o16.z = f2bf(o[j*4+2]); o16.w = f2bf(o[j*4+3]);
      *(ushort4*)(xo + j * 256) = o16;
    }
  }
}

extern "C" void kernel_launch(void* const* d_in, const int* in_sizes, int n_in,
                              void* d_out, int out_size, void* d_ws, size_t ws_size,
                              hipStream_t stream) {
  const float* x     = (const float*)d_in[0];
  const float* W     = (const float*)d_in[1];
  const float* a_src = (const float*)d_in[2];
  const float* a_dst = (const float*)d_in[3];
  const float* bias  = (const float*)d_in[4];
  const float* gamma = (const float*)d_in[5];
  const float* beta  = (const float*)d_in[6];
  float* out = (float*)d_out;

  char* ws = (char*)d_ws;
  size_t off = 0;
  auto alloc = [&](size_t bytes)->char*{
    char* p = ws + off;
    off = (off + bytes + 255) & ~(size_t)255;
    return p;
  };
  unsigned short* wt   = (unsigned short*)alloc((size_t)LL * NN * HH * 2);
  unsigned short* xb   = (unsigned short*)alloc((size_t)BT * HH * 2);
  unsigned short* hbuf = (unsigned short*)alloc((size_t)BT * NN * 2);
  float* psrc  = (float*)alloc((size_t)BT * NHEADS * NBLK * 4);
  float* pdst  = (float*)alloc((size_t)BT * NHEADS * NBLK * 4);

  wt_kernel<<<dim3(NN/32, HH/32, LL), dim3(32, 8), 0, stream>>>(W, wt);
  xconv_kernel<<<(BT * HH / 4) / 256, 256, 0, stream>>>(x, xb);

  for (int l = 0; l < LL; l++){
    gemm_kernel<<<(NN / BN) * (BT / BM), 256, 0, stream>>>(
        xb, wt + (size_t)l * NN * HH, hbuf,
        a_src + (size_t)l * NHEADS * DD, a_dst + (size_t)l * NHEADS * DD,
        psrc, pdst);
    attn_ln_kernel<<<BT / 4, 256, 0, stream>>>(hbuf, psrc, pdst,
        (l == 0) ? x : nullptr, xb,
        bias + (size_t)l * DD, gamma + (size_t)l * HH, beta + (size_t)l * HH,
        out, xb, (l == LL - 1) ? 1 : 0);
  }
}

// Round 11
// 315.320 us; speedup vs baseline: 1.4784x; 1.4267x over previous
//
#include <hip/hip_runtime.h>
#include <stdint.h>

#define TT 2048
#define BB 4
#define HH 768
#define NHEADS 4
#define DD 768
#define NN 3072   // NHEADS*DD
#define LL 3
#define BT 8192   // BB*TT
#define KNB 5
#define NBLK 12   // 64-col partial blocks per head (DD/64)

typedef __bf16 bf16x8 __attribute__((ext_vector_type(8)));
typedef float f32x4 __attribute__((ext_vector_type(4)));

__device__ __forceinline__ unsigned short f2bf(float f){
  union { float f; unsigned u; } v; v.f = f;
  unsigned u = v.u;
  return (unsigned short)((u + 0x7FFFu + ((u >> 16) & 1u)) >> 16);
}
__device__ __forceinline__ float bf2f(unsigned short h){
  union { unsigned u; float f; } v; v.u = ((unsigned)h) << 16;
  return v.f;
}
// async global->LDS, 16B per lane; LDS dest = wave-uniform base + lane*16
__device__ __forceinline__ void gload16(const unsigned short* g, unsigned short* l){
  __builtin_amdgcn_global_load_lds((const __attribute__((address_space(1))) void*)g,
                                   (__attribute__((address_space(3))) void*)l, 16, 0, 0);
}

// ---------------- W transpose + bf16 convert: W[l][k][n] fp32 -> Wt[l][n][k] bf16
__global__ void wt_kernel(const float* __restrict__ W, unsigned short* __restrict__ Wt){
  __shared__ float tile[32][33];
  int l = blockIdx.z;
  int n0 = blockIdx.x * 32, k0 = blockIdx.y * 32;
  int tx = threadIdx.x, ty = threadIdx.y; // (32,8)
  const float* Wl = W + (size_t)l * HH * NN;
  for (int r = 0; r < 4; r++)
    tile[ty + r*8][tx] = Wl[(size_t)(k0 + ty + r*8) * NN + n0 + tx];
  __syncthreads();
  unsigned short* Wtl = Wt + (size_t)l * NN * HH;
  for (int r = 0; r < 4; r++){
    int n = n0 + ty + r*8;
    Wtl[(size_t)n * HH + k0 + tx] = f2bf(tile[tx][ty + r*8]);
  }
}

// ---------------- x fp32 -> bf16 (layer 0 GEMM input)
__global__ void xconv_kernel(const float* __restrict__ x, unsigned short* __restrict__ xb){
  int i = blockIdx.x * blockDim.x + threadIdx.x;
  float4 v = ((const float4*)x)[i];
  ushort4 o;
  o.x = f2bf(v.x); o.y = f2bf(v.y); o.z = f2bf(v.z); o.w = f2bf(v.w);
  *(ushort4*)(xb + (size_t)i * 4) = o;
}

// ---------------- GEMM (R6 K-loop, FROZEN — verified best 4x):
// R12 (256² 4-phase unroll2): spilled, 92us. R15 (128² 2-phase dbuf): lost
// 3rd block/CU, 66us. R16 (256² 4-phase unroll1): 1 block/CU, 75us.
// R18 (B direct from global): +32 live VGPR across barrier -> spills, 64us.
// Lesson: this 2-barrier loop at 3 blocks/CU TLP is the measured optimum for
// K=768; every extra live register or LDS byte costs more than it buys.
#define BM 128
#define BN 128
#define BK 64

__global__ __launch_bounds__(256, 3) void gemm_kernel(
    const unsigned short* __restrict__ xb,
    const unsigned short* __restrict__ wt,
    unsigned short* __restrict__ hout,
    const float* __restrict__ a_srcl,
    const float* __restrict__ a_dstl,
    float* __restrict__ psrc,     // [BT][NHEADS][NBLK]
    float* __restrict__ pdst){
  __shared__ __align__(16) unsigned short xs[BM][BK];   // 16 KB
  __shared__ __align__(16) unsigned short wsd[BN][BK];  // 16 KB
  // XCD-aware remap: per-XCD 8-row bm band, bn-major within the band so the
  // xb band (1.6 MB) stays L2-resident and wt slices stream through.
  int id = blockIdx.x;              // 1536
  int xcd = id & 7;
  int s = id >> 3;                  // 0..191
  int bn_i = s / 8;                 // 0..23
  int bm_i = (s & 7) + xcd * 8;     // 0..63
  int bm = bm_i * BM;
  int bn = bn_i * BN;
  int tid = threadIdx.x;
  int wave = tid >> 6, lane = tid & 63;
  int m16 = lane & 15, q = lane >> 4;
  int wm = (wave >> 1) * 64, wn = (wave & 1) * 64;
  int r8 = lane >> 3, c8 = lane & 7;
  int cg = (c8 ^ r8) * 8;     // fetched chunk: position c8 holds global chunk c8^(row&7)
  const unsigned short* ga[4]; const unsigned short* gb[4];
  unsigned short* la[4]; unsigned short* lb[4];
  #pragma unroll
  for (int ss = 0; ss < 4; ss++){
    int row = wave * 32 + ss * 8;
    ga[ss] = xb + (size_t)(bm + row + r8) * HH + cg;
    gb[ss] = wt + (size_t)(bn + row + r8) * HH + cg;
    la[ss] = &xs[row][0];
    lb[ss] = &wsd[row][0];
  }
  int rd0 = ((0 + q) ^ (m16 & 7)) * 8;   // ks=0 fragment chunk offset
  int rd1 = ((4 + q) ^ (m16 & 7)) * 8;   // ks=1
  f32x4 acc[4][4] = {};
  for (int k0 = 0; k0 < HH; k0 += BK){
    #pragma unroll
    for (int ss = 0; ss < 4; ss++){
      gload16(ga[ss] + k0, la[ss]);
      gload16(gb[ss] + k0, lb[ss]);
    }
    __syncthreads();
    bf16x8 af[4], bfr[4];
    for (int i = 0; i < 4; i++)
      af[i] = __builtin_bit_cast(bf16x8, *(const uint4*)(&xs[wm + i*16 + m16][rd0]));
    for (int j = 0; j < 4; j++)
      bfr[j] = __builtin_bit_cast(bf16x8, *(const uint4*)(&wsd[wn + j*16 + m16][rd0]));
    for (int i = 0; i < 4; i++)
      for (int j = 0; j < 4; j++)
        acc[i][j] = __builtin_amdgcn_mfma_f32_16x16x32_bf16(af[i], bfr[j], acc[i][j], 0, 0, 0);
    for (int i = 0; i < 4; i++)
      af[i] = __builtin_bit_cast(bf16x8, *(const uint4*)(&xs[wm + i*16 + m16][rd1]));
    for (int j = 0; j < 4; j++)
      bfr[j] = __builtin_bit_cast(bf16x8, *(const uint4*)(&wsd[wn + j*16 + m16][rd1]));
    for (int i = 0; i < 4; i++)
      for (int j = 0; j < 4; j++)
        acc[i][j] = __builtin_amdgcn_mfma_f32_16x16x32_bf16(af[i], bfr[j], acc[i][j], 0, 0, 0);
    __syncthreads();
  }
  // C store (bf16)
  for (int i = 0; i < 4; i++){
    int row0 = bm + wm + i*16 + q*4;
    for (int j = 0; j < 4; j++){
      int col = bn + wn + j*16 + m16;
      unsigned short* hp = hout + (size_t)row0 * NN + col;
      hp[0]            = f2bf(acc[i][j][0]);
      hp[NN]           = f2bf(acc[i][j][1]);
      hp[2*(size_t)NN] = f2bf(acc[i][j][2]);
      hp[3*(size_t)NN] = f2bf(acc[i][j][3]);
    }
  }
  // fused asrc/adst partials: wave covers 64 cols = one (head, blk) slot
  int col0 = bn + wn;
  int head = col0 / DD;
  int blk  = (col0 % DD) >> 6;
  float wsrc[4], wdstw[4];
  for (int j = 0; j < 4; j++){
    int n = col0 + j*16 + m16;
    wsrc[j]  = a_srcl[n];
    wdstw[j] = a_dstl[n];
  }
  for (int i = 0; i < 4; i++){
    for (int reg = 0; reg < 4; reg++){
      float ss = 0.f, dd = 0.f;
      for (int j = 0; j < 4; j++){
        float v = acc[i][j][reg];
        ss += v * wsrc[j];
        dd += v * wdstw[j];
      }
      ss += __shfl_xor(ss, 1, 64); dd += __shfl_xor(dd, 1, 64);
      ss += __shfl_xor(ss, 2, 64); dd += __shfl_xor(dd, 2, 64);
      ss += __shfl_xor(ss, 4, 64); dd += __shfl_xor(dd, 4, 64);
      ss += __shfl_xor(ss, 8, 64); dd += __shfl_xor(dd, 8, 64);
      if (m16 == 0){
        int row = bm + wm + i*16 + q*4 + reg;
        size_t slot = (size_t)row * (NHEADS * NBLK) + head * NBLK + blk;
        psrc[slot] = ss;
        pdst[slot] = dd;
      }
    }
  }
}

// ---------------- attention + head-mean + bias + residual + layernorm
// R22 = R3's R14 body (wave-per-token, per-head interleave, zero barriers,
// zero LDS, plain __launch_bounds__(512) — NO min-waves: R9/R10 proved any
// min-waves annotation on this body triggers spill codegen, 132 MB scratch,
// 74us) with ONE change: lane owns elems {lane*8..+7} u {512+lane*4..+3}
// instead of {lane*4+j*256}. PV read per (head,k) = 1 uint4 (16B/lane,
// fully-contiguous 1KB/wave — G13 sweet spot) + 1 uint2, i.e. 40 loads
// instead of 60. All elementwise arrays use the same mapping (permutation-
// invariant for the LN sum).
__global__ __launch_bounds__(512) void attn_ln_kernel(const unsigned short* __restrict__ h,
    const float* __restrict__ psrc, const float* __restrict__ pdst,
    const float* __restrict__ xin_f32,          // non-null => layer 0 residual (fp32)
    const unsigned short* __restrict__ xin_bf,  // else residual from bf16 xb
    const float* __restrict__ bias_l,
    const float* __restrict__ gamma_l, const float* __restrict__ beta_l,
    float* __restrict__ x_out, unsigned short* __restrict__ xb_next,
    int write_f32){
  int bid = blockIdx.x;                       // 1024 blocks x 8 waves
  int grp = ((bid & 7) << 7) | (bid >> 3);    // XCD-contiguous 1024-token bands
  int wave = threadIdx.x >> 6, lane = threadIdx.x & 63;
  int token = grp * 8 + wave;
  int t = token & (TT - 1);
  int bseq = token >> 11;
  int e8 = lane * 8;          // elems e8..e8+7   (bytes 16B-contiguous)
  int e4 = 512 + lane * 4;    // elems e4..e4+3

  // srcred: lanes 0..19 hold as[k][hd] (window row k=lane>>2, head=lane&3);
  // lanes 20..23 hold ad[hd] for this token. Each sums 12 partial floats.
  float red = 0.f;
  if (lane < 24){
    const float* p;
    if (lane < 20){
      int k = lane >> 2, hd = lane & 3;
      int row = min(max(t - 2 + k, 0), TT - 1);
      p = psrc + ((size_t)(bseq * TT + row) * NHEADS + hd) * NBLK;
    } else {
      int hd = lane - 20;
      p = pdst + ((size_t)(bseq * TT + t) * NHEADS + hd) * NBLK;
    }
    float4 a = *(const float4*)(p);
    float4 b = *(const float4*)(p + 4);
    float4 d = *(const float4*)(p + 8);
    red = a.x+a.y+a.z+a.w + b.x+b.y+b.z+b.w + d.x+d.y+d.z+d.w;
  }

  // per-head softmax (redundant across lanes; shfl with uniform idx ~ free)
  // + PV accumulate, per-head interleaved (R14 ordering — measured best).
  const unsigned short* hrow = h + (size_t)(bseq * TT) * NN;
  float y[12] = {};
  #pragma unroll
  for (int hd = 0; hd < NHEADS; hd++){
    float ad = __shfl(red, 20 + hd, 64);
    float sc[KNB];
    float mx = -3.0e38f;
    #pragma unroll
    for (int k = 0; k < KNB; k++){
      int tn = t + k - 2;                 // wave-uniform branch
      if (tn >= 0 && tn < TT){
        float s = __shfl(red, k * 4 + hd, 64) + ad;
        s = s > 0.f ? s : 0.2f * s;       // leaky_relu 0.2
        sc[k] = s; mx = fmaxf(mx, s);
      } else sc[k] = -3.0e38f;
    }
    float den = 0.f;
    #pragma unroll
    for (int k = 0; k < KNB; k++){
      float e = (sc[k] > -1.0e38f) ? __expf(sc[k] - mx) : 0.f;
      sc[k] = e; den += e;
    }
    float inv = 0.25f / den;              // fold 1/HEADS into attn
    #pragma unroll
    for (int k = 0; k < KNB; k++){
      int g = t + k - 2;
      g = min(max(g, 0), TT - 1);
      const unsigned short* hp = hrow + (size_t)g * NN + hd * DD;
      float a = sc[k] * inv;
      uint4 u = *(const uint4*)(hp + e8);
      uint2 v = *(const uint2*)(hp + e4);
      const unsigned short* us = (const unsigned short*)&u;
      const unsigned short* vs = (const unsigned short*)&v;
      #pragma unroll
      for (int e = 0; e < 8; e++) y[e]   += a * bf2f(us[e]);
      #pragma unroll
      for (int e = 0; e < 4; e++) y[8+e] += a * bf2f(vs[e]);
    }
  }

  // residual + bias, accumulate LN stats (same lane mapping)
  float xr[12], bb[12];
  if (xin_f32){
    const float* xp = xin_f32 + (size_t)token * HH;
    *(float4*)&xr[0] = *(const float4*)(xp + e8);
    *(float4*)&xr[4] = *(const float4*)(xp + e8 + 4);
    *(float4*)&xr[8] = *(const float4*)(xp + e4);
  } else {
    const unsigned short* xp = xin_bf + (size_t)token * HH;
    uint4 u = *(const uint4*)(xp + e8);
    uint2 v = *(const uint2*)(xp + e4);
    const unsigned short* us = (const unsigned short*)&u;
    const unsigned short* vs = (const unsigned short*)&v;
    #pragma unroll
    for (int e = 0; e < 8; e++) xr[e]   = bf2f(us[e]);
    #pragma unroll
    for (int e = 0; e < 4; e++) xr[8+e] = bf2f(vs[e]);
  }
  { const float* p = bias_l;
    *(float4*)&bb[0] = *(const float4*)(p + e8);
    *(float4*)&bb[4] = *(const float4*)(p + e8 + 4);
    *(float4*)&bb[8] = *(const float4*)(p + e4); }
  float s = 0.f, sq = 0.f;
  #pragma unroll
  for (int e = 0; e < 12; e++){
    float zz = y[e] + bb[e] + xr[e];
    y[e] = zz; s += zz; sq += zz * zz;
  }
  // wave-level LN reduce (no LDS, no barrier)
  #pragma unroll
  for (int off = 32; off > 0; off >>= 1){
    s  += __shfl_xor(s, off, 64);
    sq += __shfl_xor(sq, off, 64);
  }
  float mean = s * (1.f / HH);
  float var = sq * (1.f / HH) - mean * mean;
  float rstd = rsqrtf(var + 1e-5f);

  float gr[12], br[12];
  { const float* p = gamma_l;
    *(float4*)&gr[0] = *(const float4*)(p + e8);
    *(float4*)&gr[4] = *(const float4*)(p + e8 + 4);
    *(float4*)&gr[8] = *(const float4*)(p + e4); }
  { const float* p = beta_l;
    *(float4*)&br[0] = *(const float4*)(p + e8);
    *(float4*)&br[4] = *(const float4*)(p + e8 + 4);
    *(float4*)&br[8] = *(const float4*)(p + e4); }

  float o[12];
  #pragma unroll
  for (int e = 0; e < 12; e++)
    o[e] = (y[e] - mean) * rstd * gr[e] + br[e];

  if (write_f32){
    float* xo = x_out + (size_t)token * HH;
    *(float4*)(xo + e8)     = *(float4*)&o[0];
    *(float4*)(xo + e8 + 4) = *(float4*)&o[4];
    *(float4*)(xo + e4)     = *(float4*)&o[8];
  } else {
    unsigned short* xo = xb_next + (size_t)token * HH;
    unsigned short o16[8];
    #pragma unroll
    for (int e = 0; e < 8; e++) o16[e] = f2bf(o[e]);
    *(uint4*)(xo + e8) = *(uint4*)&o16[0];
    ushort4 o4;
    o4.x = f2bf(o[8]); o4.y = f2bf(o[9]); o4.z = f2bf(o[10]); o4.w = f2bf(o[11]);
    *(ushort4*)(xo + e4) = o4;
  }
}

extern "C" void kernel_launch(void* const* d_in, const int* in_sizes, int n_in,
                              void* d_out, int out_size, void* d_ws, size_t ws_size,
                              hipStream_t stream) {
  const float* x     = (const float*)d_in[0];
  const float* W     = (const float*)d_in[1];
  const float* a_src = (const float*)d_in[2];
  const float* a_dst = (const float*)d_in[3];
  const float* bias  = (const float*)d_in[4];
  const float* gamma = (const float*)d_in[5];
  const float* beta  = (const float*)d_in[6];
  float* out = (float*)d_out;

  char* ws = (char*)d_ws;
  size_t off = 0;
  auto alloc = [&](size_t bytes)->char*{
    char* p = ws + off;
    off = (off + bytes + 255) & ~(size_t)255;
    return p;
  };
  unsigned short* wt   = (unsigned short*)alloc((size_t)LL * NN * HH * 2);
  unsigned short* xb   = (unsigned short*)alloc((size_t)BT * HH * 2);
  unsigned short* hbuf = (unsigned short*)alloc((size_t)BT * NN * 2);
  float* psrc  = (float*)alloc((size_t)BT * NHEADS * NBLK * 4);
  float* pdst  = (float*)alloc((size_t)BT * NHEADS * NBLK * 4);

  wt_kernel<<<dim3(NN/32, HH/32, LL), dim3(32, 8), 0, stream>>>(W, wt);
  xconv_kernel<<<(BT * HH / 4) / 256, 256, 0, stream>>>(x, xb);

  for (int l = 0; l < LL; l++){
    gemm_kernel<<<(NN / BN) * (BT / BM), 256, 0, stream>>>(
        xb, wt + (size_t)l * NN * HH, hbuf,
        a_src + (size_t)l * NHEADS * DD, a_dst + (size_t)l * NHEADS * DD,
        psrc, pdst);
    attn_ln_kernel<<<BT / 8, 512, 0, stream>>>(hbuf, psrc, pdst,
        (l == 0) ? x : nullptr, xb,
        bias + (size_t)l * DD, gamma + (size_t)l * HH, beta + (size_t)l * HH,
        out, xb, (l == LL - 1) ? 1 : 0);
  }
}